// Round 1
// baseline (1501.695 us; speedup 1.0000x reference)
//
#include <hip/hip_runtime.h>
#include <hip/hip_fp16.h>

#define N_NODES 16384
#define SEQ_L   8
#define DIM_D   256
#define DIM_H   256
#define DIM_R   64

typedef float    f32x4 __attribute__((ext_vector_type(4)));
typedef _Float16 f16x8 __attribute__((ext_vector_type(8)));
typedef _Float16 f16x4 __attribute__((ext_vector_type(4)));

__device__ __forceinline__ float fsig(float x) {
    // 1/(1+e^-x) via fast exp + rcp (error ~1e-6, fine vs 2e-2 tolerance)
    return __builtin_amdgcn_rcpf(1.f + __expf(-x));
}
__device__ __forceinline__ float ftanh(float x) {
    // tanh(x) = 1 - 2/(e^{2x}+1); saturates correctly at +/-inf
    return 1.f - 2.f * __builtin_amdgcn_rcpf(1.f + __expf(2.f * x));
}

// ---------------- prep: f32 -> f16 conversion of weights / rel ----------------
__global__ void cvt6_kernel(const float* __restrict__ s0, const float* __restrict__ s1,
                            const float* __restrict__ s2, const float* __restrict__ s3,
                            const float* __restrict__ s4, const float* __restrict__ s5,
                            _Float16* __restrict__ d0, _Float16* __restrict__ d1,
                            _Float16* __restrict__ d2, _Float16* __restrict__ d3,
                            _Float16* __restrict__ d4, _Float16* __restrict__ d5,
                            int n0, int n1, int n2, int n3, int n4, int n5) {
    const float* S[6] = {s0, s1, s2, s3, s4, s5};
    _Float16*    D[6] = {d0, d1, d2, d3, d4, d5};
    int          Q[6] = {n0 >> 2, n1 >> 2, n2 >> 2, n3 >> 2, n4 >> 2, n5 >> 2};
    const int stride = gridDim.x * blockDim.x;
    const int t0 = blockIdx.x * blockDim.x + threadIdx.x;
    for (int s = 0; s < 6; ++s) {
        const f32x4* src = (const f32x4*)S[s];
        f16x4*       dst = (f16x4*)D[s];
        for (int i = t0; i < Q[s]; i += stride) {
            f32x4 v = src[i];
            f16x4 h;
            h[0] = (_Float16)v[0]; h[1] = (_Float16)v[1];
            h[2] = (_Float16)v[2]; h[3] = (_Float16)v[3];
            dst[i] = h;
        }
    }
}

// ---------------- fused LSTM over 8 timesteps, 64 nodes per block ----------------
// 512 threads = 8 waves. Wave w owns hidden units [w*32, w*32+32) for all 4 gates
// and all 64 rows. acc[rowtile 0..3][gate 0..3][hidtile 0..1] (f32x4 each) = 128 VGPR.
__global__ __launch_bounds__(512, 2) void lstm_kernel(
    const float* __restrict__ left, const float* __restrict__ right,
    const _Float16* __restrict__ wih_l, const _Float16* __restrict__ whh_l,
    const _Float16* __restrict__ wih_r, const _Float16* __restrict__ whh_r,
    const float* __restrict__ bih_l, const float* __restrict__ bhh_l,
    const float* __restrict__ bih_r, const float* __restrict__ bhh_r,
    _Float16* __restrict__ hl_out, _Float16* __restrict__ hr_out) {

    const int side = blockIdx.y;
    const float*    chain = side ? right : left;
    const _Float16* Wih   = side ? wih_r : wih_l;
    const _Float16* Whh   = side ? whh_r : whh_l;
    const float*    bih   = side ? bih_r : bih_l;
    const float*    bhh   = side ? bhh_r : bhh_l;
    _Float16*       hout  = side ? hr_out : hl_out;

    // LDS tiles, logical [64 rows][256 k] f16, element (row,k) stored at
    // row*256 + (k ^ ((row&7)<<3))  -> spreads the 512B row stride across banks.
    __shared__ _Float16 lds_x[64 * 256] __attribute__((aligned(16)));
    __shared__ _Float16 lds_h[64 * 256] __attribute__((aligned(16)));

    const int tid  = threadIdx.x;
    const int lane = tid & 63;
    const int wave = tid >> 6;        // 0..7
    const int l15  = lane & 15;
    const int l4   = lane >> 4;       // 0..3
    const int klb  = l4 * 8;          // per-lane K offset inside a K=32 slab
    const int node0 = blockIdx.x * 64;
    const int hid0  = wave * 32;

    const f32x4 FZ = {0.f, 0.f, 0.f, 0.f};

    // B-fragment base offsets (element index into W[1024][256]) and fused bias
    int   boff[4][2];
    float bias[4][2];
#pragma unroll
    for (int g = 0; g < 4; ++g)
#pragma unroll
        for (int ht = 0; ht < 2; ++ht) {
            int col = g * 256 + hid0 + ht * 16 + l15;
            boff[g][ht] = col * 256 + klb;
            bias[g][ht] = bih[col] + bhh[col];
        }

    f32x4 acc[4][4][2];   // [rowtile][gate][hidtile]
    f32x4 cst[4][2];      // cell state, f32
#pragma unroll
    for (int rt = 0; rt < 4; ++rt)
#pragma unroll
        for (int ht = 0; ht < 2; ++ht) cst[rt][ht] = FZ;

    auto do_gemm = [&](const _Float16* lds, const _Float16* W) {
#pragma unroll
        for (int ks = 0; ks < 8; ++ks) {
            const int kk = ks * 32 + klb;
            f16x8 a[4];
#pragma unroll
            for (int rt = 0; rt < 4; ++rt) {
                int row = rt * 16 + l15;
                int off = row * 256 + (kk ^ ((row & 7) << 3));
                a[rt] = *(const f16x8*)&lds[off];
            }
#pragma unroll
            for (int g = 0; g < 4; ++g)
#pragma unroll
                for (int ht = 0; ht < 2; ++ht) {
                    f16x8 b = *(const f16x8*)&W[boff[g][ht] + ks * 32];
#pragma unroll
                    for (int rt = 0; rt < 4; ++rt)
                        acc[rt][g][ht] = __builtin_amdgcn_mfma_f32_16x16x32_f16(
                            a[rt], b, acc[rt][g][ht], 0, 0, 0);
                }
        }
    };

#pragma unroll 1
    for (int t = 0; t < SEQ_L; ++t) {
        // ---- stage x_t: [64 rows][256] f32 -> f16 swizzled LDS, coalesced ----
#pragma unroll
        for (int it = 0; it < 8; ++it) {
            int e4  = it * 512 + tid;      // float4 index, 0..4095
            int row = e4 >> 6;             // 64 float4 per row
            int kq  = (e4 & 63) << 2;
            f32x4 v = *(const f32x4*)(chain +
                      (size_t)(node0 + row) * (SEQ_L * DIM_D) + t * DIM_D + kq);
            f16x4 h4;
            h4[0] = (_Float16)v[0]; h4[1] = (_Float16)v[1];
            h4[2] = (_Float16)v[2]; h4[3] = (_Float16)v[3];
            int idx = row * 256 + (kq ^ ((row & 7) << 3));
            *(f16x4*)&lds_x[idx] = h4;
        }
        __syncthreads();   // x_t staged; h(t-1) writes from prev iter visible

#pragma unroll
        for (int rt = 0; rt < 4; ++rt)
#pragma unroll
            for (int g = 0; g < 4; ++g)
#pragma unroll
                for (int ht = 0; ht < 2; ++ht) acc[rt][g][ht] = FZ;

        do_gemm(lds_x, Wih);
        if (t > 0) do_gemm(lds_h, Whh);   // h(0) == 0
        __syncthreads();   // all LDS reads done before h(t) overwrites lds_h

        // ---- gates + state update (PyTorch order i,f,g,o) ----
#pragma unroll
        for (int rt = 0; rt < 4; ++rt)
#pragma unroll
            for (int ht = 0; ht < 2; ++ht)
#pragma unroll
                for (int r = 0; r < 4; ++r) {
                    float gi = acc[rt][0][ht][r] + bias[0][ht];
                    float gf = acc[rt][1][ht][r] + bias[1][ht];
                    float gg = acc[rt][2][ht][r] + bias[2][ht];
                    float go = acc[rt][3][ht][r] + bias[3][ht];
                    float ii = fsig(gi), ff = fsig(gf);
                    float gt = ftanh(gg), oo = fsig(go);
                    float c = ff * cst[rt][ht][r] + ii * gt;
                    cst[rt][ht][r] = c;
                    float h = oo * ftanh(c);
                    int rowl = rt * 16 + l4 * 4 + r;      // C/D: row=(lane>>4)*4+reg
                    int hid  = hid0 + ht * 16 + l15;      //      col=lane&15
                    lds_h[rowl * 256 + (hid ^ ((rowl & 7) << 3))] = (_Float16)h;
                    if (t == SEQ_L - 1)
                        hout[(size_t)(node0 + rowl) * 256 + hid] = (_Float16)h;
                }
        // no barrier: next-iter staging writes lds_x (disjoint); barrier at top
        // of next iter orders lds_h writes vs. reads.
    }
}

// ---------------- encoder: tanh([hl|hr|rel] @ Wenc^T + benc) ----------------
__global__ __launch_bounds__(256, 2) void enc_kernel(
    const _Float16* __restrict__ hl, const _Float16* __restrict__ hr,
    const _Float16* __restrict__ rel16, const _Float16* __restrict__ Wenc16,
    const float* __restrict__ benc, float* __restrict__ out) {

    const int tid  = threadIdx.x;
    const int lane = tid & 63;
    const int wave = tid >> 6;    // 0..3
    const int l15  = lane & 15;
    const int l4   = lane >> 4;
    const int klb  = l4 * 8;
    const int row0 = blockIdx.x * 64;
    const int colw = wave * 64;

    const f32x4 FZ = {0.f, 0.f, 0.f, 0.f};
    f32x4 acc[4][4];   // [rowtile][coltile]
#pragma unroll
    for (int rt = 0; rt < 4; ++rt)
#pragma unroll
        for (int ct = 0; ct < 4; ++ct) acc[rt][ct] = FZ;

    float bce[4];
#pragma unroll
    for (int ct = 0; ct < 4; ++ct) bce[ct] = benc[colw + ct * 16 + l15];

    for (int ks = 0; ks < 18; ++ks) {   // K = 576 = 256(hl) + 256(hr) + 64(rel)
        const int kk = ks * 32 + klb;
        f16x8 a[4];
#pragma unroll
        for (int rt = 0; rt < 4; ++rt) {
            int row = row0 + rt * 16 + l15;
            const _Float16* p;
            if (ks < 8)       p = hl    + (size_t)row * 256 + kk;
            else if (ks < 16) p = hr    + (size_t)row * 256 + (kk - 256);
            else              p = rel16 + (size_t)row * 64  + (kk - 512);
            a[rt] = *(const f16x8*)p;
        }
#pragma unroll
        for (int ct = 0; ct < 4; ++ct) {
            int col = colw + ct * 16 + l15;
            f16x8 b = *(const f16x8*)&Wenc16[(size_t)col * 576 + kk];
#pragma unroll
            for (int rt = 0; rt < 4; ++rt)
                acc[rt][ct] = __builtin_amdgcn_mfma_f32_16x16x32_f16(
                    a[rt], b, acc[rt][ct], 0, 0, 0);
        }
    }

#pragma unroll
    for (int rt = 0; rt < 4; ++rt)
#pragma unroll
        for (int ct = 0; ct < 4; ++ct)
#pragma unroll
            for (int r = 0; r < 4; ++r) {
                int row = row0 + rt * 16 + l4 * 4 + r;
                int col = colw + ct * 16 + l15;
                out[(size_t)row * 256 + col] = ftanh(acc[rt][ct][r] + bce[ct]);
            }
}

extern "C" void kernel_launch(void* const* d_in, const int* in_sizes, int n_in,
                              void* d_out, int out_size, void* d_ws, size_t ws_size,
                              hipStream_t stream) {
    const float* left  = (const float*)d_in[0];
    const float* right = (const float*)d_in[1];
    const float* rel   = (const float*)d_in[2];
    const float* Wih_l = (const float*)d_in[3];
    const float* Whh_l = (const float*)d_in[4];
    const float* bih_l = (const float*)d_in[5];
    const float* bhh_l = (const float*)d_in[6];
    const float* Wih_r = (const float*)d_in[7];
    const float* Whh_r = (const float*)d_in[8];
    const float* bih_r = (const float*)d_in[9];
    const float* bhh_r = (const float*)d_in[10];
    const float* Wenc  = (const float*)d_in[11];
    const float* benc  = (const float*)d_in[12];
    float* out = (float*)d_out;

    char* ws = (char*)d_ws;
    _Float16* wih_l16 = (_Float16*)(ws);
    _Float16* whh_l16 = (_Float16*)(ws + 512 * 1024);
    _Float16* wih_r16 = (_Float16*)(ws + 1024 * 1024);
    _Float16* whh_r16 = (_Float16*)(ws + 1536 * 1024);
    _Float16* wenc16  = (_Float16*)(ws + 2048 * 1024);
    _Float16* rel16   = (_Float16*)(ws + 2560 * 1024);
    _Float16* hl16    = (_Float16*)(ws + 4608 * 1024);
    _Float16* hr16    = (_Float16*)(ws + 4608 * 1024 + 8192 * 1024);
    (void)in_sizes; (void)n_in; (void)out_size; (void)ws_size;

    hipLaunchKernelGGL(cvt6_kernel, dim3(512), dim3(256), 0, stream,
                       Wih_l, Whh_l, Wih_r, Whh_r, Wenc, rel,
                       wih_l16, whh_l16, wih_r16, whh_r16, wenc16, rel16,
                       4 * DIM_H * DIM_D, 4 * DIM_H * DIM_H,
                       4 * DIM_H * DIM_D, 4 * DIM_H * DIM_H,
                       DIM_H * (2 * DIM_H + DIM_R), N_NODES * DIM_R);

    hipLaunchKernelGGL(lstm_kernel, dim3(N_NODES / 64, 2), dim3(512), 0, stream,
                       left, right, wih_l16, whh_l16, wih_r16, whh_r16,
                       bih_l, bhh_l, bih_r, bhh_r, hl16, hr16);

    hipLaunchKernelGGL(enc_kernel, dim3(N_NODES / 64), dim3(256), 0, stream,
                       hl16, hr16, rel16, wenc16, benc, out);
}